// Round 12
// baseline (125.660 us; speedup 1.0000x reference)
//
#include <hip/hip_runtime.h>
#include <hip/hip_bf16.h>
#include <stdint.h>

typedef unsigned short ushort_t;

#define BB 4
#define SS 4096
#define DD 2048
#define KKC 64      // K channels
#define HH 32
#define NT (BB*SS)  // 16384 tokens
#define NQKV 192
#define QB 32       // tokens per k_qkv block

// dynamic LDS: 2 bufs x (B 24576 + x 8192) = 65536 B
#define BUF2 32768
#define XOFF 24576

typedef float f32x4 __attribute__((ext_vector_type(4)));
typedef short s16x8 __attribute__((ext_vector_type(8)));

__device__ __forceinline__ ushort_t f2bf(float f) {
    union { float f; uint32_t u; } c; c.f = f;
    uint32_t u = c.u + 0x7fffu + ((c.u >> 16) & 1u);
    return (ushort_t)(u >> 16);
}
__device__ __forceinline__ float bf2f(ushort_t b) {
    union { uint32_t u; float f; } c; c.u = (uint32_t)b << 16; return c.f;
}

__device__ __forceinline__ uint32_t cvtpk(float lo, float hi) {
    uint32_t r;
    asm("v_cvt_pk_bf16_f32 %0, %1, %2" : "=v"(r) : "v"(lo), "v"(hi));
    return r;
}

// D = A(16x32) * B(32x16) + D, bf16 inputs, f32 acc.
// A lane map: row = l&15, k = 8*(l>>4)+e. B: col = l&15, k = 8*(l>>4)+e.
// C/D: col = l&15, row = 4*(l>>4)+reg.
__device__ __forceinline__ void mfma16(f32x4& d, s16x8 a, s16x8 b) {
    asm volatile("v_mfma_f32_16x16x32_bf16 %0, %1, %2, %0" : "+v"(d) : "v"(a), "v"(b));
}

// async global->LDS, 16B per lane; lds dest wave-uniform base (HW adds lane*16).
__device__ __forceinline__ void gload_lds16(const void* gsrc, void* ldst) {
    __builtin_amdgcn_global_load_lds(
        (const __attribute__((address_space(1))) unsigned int*)gsrc,
        (__attribute__((address_space(3))) unsigned int*)ldst,
        16, 0, 0);
}

// ---------------- weight pre-convert to fragment-linear bf16 ----------------
// W1' entry E (16B): lane=E&63, f=(E>>6)%12, g=(E>>6)/12 (g=kblk 0..63)
//   col=f*16+(lane&15); k0=g*32+8*(lane>>4); holds qkv_w[col][k]*norm_w[k]
// W2 entry E: lane=E&63, kk=(E>>6)&1, F=(E>>6)>>1
//   n=F*16+(lane&15); k0=kk*32+8*(lane>>4); holds out_w[n][k0..k0+7]
__global__ __launch_bounds__(256) void k_pre(
    const float* __restrict__ qkv_w, const float* __restrict__ nw,
    const float* __restrict__ out_w,
    ushort_t* __restrict__ W1, ushort_t* __restrict__ W2) {
    int E = blockIdx.x * 256 + threadIdx.x;
    if (E < 49152) {
        int lane = E & 63; int rest = E >> 6;
        int f = rest % 12, g = rest / 12;
        int col = f * 16 + (lane & 15);
        int k0 = g * 32 + 8 * (lane >> 4);
        const float* src = qkv_w + (size_t)col * DD + k0;
        const float* wp = nw + k0;
        union { ushort_t u[8]; uint4 v; } cv;
        #pragma unroll
        for (int e = 0; e < 8; ++e) cv.u[e] = f2bf(src[e] * wp[e]);
        *(uint4*)(W1 + (size_t)E * 8) = cv.v;
    } else {
        int E2 = E - 49152;   // 16384 entries
        int lane = E2 & 63; int rest = E2 >> 6;
        int kk = rest & 1, F = rest >> 1;
        int n = F * 16 + (lane & 15);
        int k0 = kk * 32 + 8 * (lane >> 4);
        const float* src = out_w + (size_t)n * KKC + k0;
        union { ushort_t u[8]; uint4 v; } cv;
        #pragma unroll
        for (int e = 0; e < 8; ++e) cv.u[e] = f2bf(src[e]);
        *(uint4*)(W2 + (size_t)E2 * 8) = cv.v;
    }
}

// ------- per-col sums: S[col]=sum_k bf16(qkv_w*nw), qb2[col]=sum nb*qkv_w + qkv_b
__global__ __launch_bounds__(256) void k_colsum(
    const float* __restrict__ qkv_w, const float* __restrict__ nw,
    const float* __restrict__ nb, const float* __restrict__ qkv_b,
    float* __restrict__ S, float* __restrict__ qb2) {
    int col = blockIdx.x * 4 + (threadIdx.x >> 6);   // 48 blocks -> 192 cols
    int lane = threadIdx.x & 63;
    float s = 0.f, qb = 0.f;
    for (int j = 0; j < 32; ++j) {
        int k = j * 64 + lane;
        float w = qkv_w[(size_t)col * DD + k];
        s += bf2f(f2bf(w * nw[k]));
        qb += nb[k] * w;
    }
    #pragma unroll
    for (int off = 32; off >= 1; off >>= 1) {
        s += __shfl_xor(s, off);
        qb += __shfl_xor(qb, off);
    }
    if (lane == 0) { S[col] = s; qb2[col] = qb + qkv_b[col]; }
}

// ------- fused (LN-folded) QKV GEMM + stats + feature map + kv partials -----
// 32 tokens/block, grid 512 -> 2 blocks/CU (16 waves/CU). 512 thr = 8 waves:
// rg = wave&1 (16 rows), ch = wave>>1 (48 cols = 3 frags).
// BK=64, 32 steps. DOUBLE-buffered staging, counted s_waitcnt vmcnt(4) +
// raw s_barrier: stage(t+1) issued before the wait for stage(t), so loads
// stay in flight a full step; barrier never drains fresh loads.
// 4 gload_lds/thread/stage (B 3 + x 1).
__global__ __launch_bounds__(512, 4) void k_qkv(
    const float* __restrict__ x, const ushort_t* __restrict__ W1,
    const float* __restrict__ S, const float* __restrict__ qb2,
    const float* __restrict__ fm_w, const float* __restrict__ fm_b,
    float* __restrict__ qfeat,          // [NT][64]
    float* __restrict__ kvpart)         // [512 blocks][192]
{
    extern __shared__ __align__(16) char dynlds[];   // 65536 B
    __shared__ float kvred[32][16][6];   // 12288 B
    __shared__ float stats4[4][QB][2];   // 1024 B
    __shared__ float stats[QB][2];       // 256 B

    const int tid = threadIdx.x;
    const int wave = tid >> 6, lane = tid & 63;
    const int rg = wave & 1, ch = wave >> 1;
    const int m0 = blockIdx.x * QB;

    const int rloc = rg * 16 + (lane & 15);
    const int q4 = lane >> 4;
    const int swz = rloc & 7;
    const int fbase = ch * 3;

    // x staging: 512 16B-entries/step, 1 per thread
    const int row0 = tid >> 4;
    const int slot0 = (tid & 15) ^ (row0 & 7);      // pre-swizzled source
    const size_t xg0 = (size_t)(m0 + row0) * DD + slot0 * 4;
    const int xd0 = wave * 1024;                    // wave-uniform byte base

    f32x4 acc[3];
    #pragma unroll
    for (int j = 0; j < 3; ++j) acc[j] = (f32x4){0.f, 0.f, 0.f, 0.f};
    float st1 = 0.f, st2 = 0.f;

#define STAGE(T, OB) do { \
        char* bB_ = dynlds + (OB); \
        char* bX_ = dynlds + (OB) + XOFF; \
        _Pragma("unroll") \
        for (int i_ = 0; i_ < 3; ++i_) { \
            int eb_ = i_ * 512 + wave * 64; \
            gload_lds16((const char*)W1 + ((size_t)(T) * 1536 + eb_ + lane) * 16, \
                        bB_ + eb_ * 16); \
        } \
        gload_lds16(x + xg0 + (size_t)(T) * 64, bX_ + xd0); \
    } while (0)

#define STEP_BODY(OC, T) do { \
        const s16x8* bb_ = (const s16x8*)(dynlds + (OC)); \
        const float* xb_ = (const float*)(dynlds + (OC) + XOFF) + rloc * 64; \
        const bool doStats_ = (((T) & 3) == ch); \
        s16x8 afr0_, afr1_; \
        { \
            int sg0_ = 2 * q4, sg1_ = 8 + 2 * q4; \
            float4 a0_ = *(const float4*)(xb_ + ((sg0_    ) ^ swz) * 4); \
            float4 a1_ = *(const float4*)(xb_ + ((sg0_ + 1) ^ swz) * 4); \
            float4 b0_ = *(const float4*)(xb_ + ((sg1_    ) ^ swz) * 4); \
            float4 b1_ = *(const float4*)(xb_ + ((sg1_ + 1) ^ swz) * 4); \
            if (doStats_) { \
                st1 += a0_.x+a0_.y+a0_.z+a0_.w + a1_.x+a1_.y+a1_.z+a1_.w \
                     + b0_.x+b0_.y+b0_.z+b0_.w + b1_.x+b1_.y+b1_.z+b1_.w; \
                st2 += a0_.x*a0_.x+a0_.y*a0_.y+a0_.z*a0_.z+a0_.w*a0_.w \
                     + a1_.x*a1_.x+a1_.y*a1_.y+a1_.z*a1_.z+a1_.w*a1_.w \
                     + b0_.x*b0_.x+b0_.y*b0_.y+b0_.z*b0_.z+b0_.w*b0_.w \
                     + b1_.x*b1_.x+b1_.y*b1_.y+b1_.z*b1_.z+b1_.w*b1_.w; \
            } \
            union { uint32_t w[4]; s16x8 v; } c0_, c1_; \
            c0_.w[0] = cvtpk(a0_.x, a0_.y); c0_.w[1] = cvtpk(a0_.z, a0_.w); \
            c0_.w[2] = cvtpk(a1_.x, a1_.y); c0_.w[3] = cvtpk(a1_.z, a1_.w); \
            c1_.w[0] = cvtpk(b0_.x, b0_.y); c1_.w[1] = cvtpk(b0_.z, b0_.w); \
            c1_.w[2] = cvtpk(b1_.x, b1_.y); c1_.w[3] = cvtpk(b1_.z, b1_.w); \
            afr0_ = c0_.v; afr1_ = c1_.v; \
        } \
        _Pragma("unroll") \
        for (int j_ = 0; j_ < 3; ++j_) { \
            s16x8 w0_ = bb_[(fbase + j_) * 64 + lane]; \
            s16x8 w1_ = bb_[(12 + fbase + j_) * 64 + lane]; \
            mfma16(acc[j_], afr0_, w0_); \
            mfma16(acc[j_], afr1_, w1_); \
        } \
    } while (0)

    STAGE(0, 0);
    for (int t = 0; t < 31; ++t) {
        STAGE(t + 1, ((t + 1) & 1) * BUF2);           // into other buffer
        asm volatile("s_waitcnt vmcnt(4)" ::: "memory");  // stage(t) landed
        __builtin_amdgcn_s_barrier();                 // buf(t) ready block-wide
        __builtin_amdgcn_sched_barrier(0);
        STEP_BODY((t & 1) * BUF2, t);
        __builtin_amdgcn_s_barrier();                 // buf(t) reads done
    }
    asm volatile("s_waitcnt vmcnt(0)" ::: "memory");
    __builtin_amdgcn_s_barrier();
    __builtin_amdgcn_sched_barrier(0);
    STEP_BODY((31 & 1) * BUF2, 31);

    // ---- stats: reduce q4 groups, publish per-ch partials
    st1 += __shfl_xor(st1, 16); st2 += __shfl_xor(st2, 16);
    st1 += __shfl_xor(st1, 32); st2 += __shfl_xor(st2, 32);
    if (lane < 16) { stats4[ch][rloc][0] = st1; stats4[ch][rloc][1] = st2; }
    __syncthreads();    // all LDS reads consumed; stats4 visible

    // ---- C -> LDS overlay (clobbers staging bufs; safe now) + final stats
    float (*cep)[NQKV] = (float (*)[NQKV])dynlds;     // 32x192 f32 = 24 KB
    #pragma unroll
    for (int j = 0; j < 3; ++j) {
        int col = (fbase + j) * 16 + (lane & 15);
        int rbase = rg * 16 + (lane >> 4) * 4;
        #pragma unroll
        for (int r = 0; r < 4; ++r)
            cep[rbase + r][col] = acc[j][r];
    }
    if (tid < QB) {
        float s1 = stats4[0][tid][0] + stats4[1][tid][0] + stats4[2][tid][0] + stats4[3][tid][0];
        float s2 = stats4[0][tid][1] + stats4[1][tid][1] + stats4[2][tid][1] + stats4[3][tid][1];
        float mu = s1 * (1.f / DD);
        float var = s2 * (1.f / DD) - mu * mu;
        stats[tid][0] = mu;
        stats[tid][1] = rsqrtf(var + 1e-5f);
    }
    __syncthreads();

    // ---- per (token, head): LN-affine + feature map + qfeat + kv partials
    const int h = tid & 31, gg = tid >> 5;     // gg 0..15, 2 tokens each
    const float fm00 = fm_w[0], fm01 = fm_w[1], fm10 = fm_w[2], fm11 = fm_w[3];
    const float fb0 = fm_b[0], fb1 = fm_b[1];
    const float Sq0 = S[2*h],      Sq1 = S[2*h+1],      cq0 = qb2[2*h],      cq1 = qb2[2*h+1];
    const float Sk0 = S[64+2*h],   Sk1 = S[64+2*h+1],   ck0 = qb2[64+2*h],   ck1 = qb2[64+2*h+1];
    const float Sv0 = S[128+2*h],  Sv1 = S[128+2*h+1],  cv0 = qb2[128+2*h],  cv1 = qb2[128+2*h+1];
    float kv00=0, kv01=0, kv10=0, kv11=0, ks0=0, ks1=0;
    #pragma unroll
    for (int i = 0; i < 2; ++i) {
        int tt = gg * 2 + i;
        float mu = stats[tt][0], rs = stats[tt][1];
        float f = mu * rs;
        float q0 = rs * cep[tt][2*h]      - f * Sq0 + cq0;
        float q1 = rs * cep[tt][2*h+1]    - f * Sq1 + cq1;
        float k0 = rs * cep[tt][64+2*h]   - f * Sk0 + ck0;
        float k1 = rs * cep[tt][64+2*h+1] - f * Sk1 + ck1;
        float v0 = rs * cep[tt][128+2*h]  - f * Sv0 + cv0;
        float v1 = rs * cep[tt][128+2*h+1]- f * Sv1 + cv1;
        float qp0 = fmaxf(fm00*q0 + fm01*q1 + fb0, 0.f);
        float qp1 = fmaxf(fm10*q0 + fm11*q1 + fb1, 0.f);
        float kp0 = fmaxf(fm00*k0 + fm01*k1 + fb0, 0.f);
        float kp1 = fmaxf(fm10*k0 + fm11*k1 + fb1, 0.f);
        *(float2*)(qfeat + (size_t)(m0 + tt) * KKC + 2*h) = make_float2(qp0, qp1);
        kv00 += kp0*v0; kv01 += kp0*v1; kv10 += kp1*v0; kv11 += kp1*v1;
        ks0 += kp0; ks1 += kp1;
    }
    kvred[h][gg][0]=kv00; kvred[h][gg][1]=kv01; kvred[h][gg][2]=kv10;
    kvred[h][gg][3]=kv11; kvred[h][gg][4]=ks0;  kvred[h][gg][5]=ks1;
    __syncthreads();
    if (tid < 192) {
        int h2 = tid / 6, j = tid % 6;
        float s = 0.f;
        #pragma unroll
        for (int g2 = 0; g2 < 16; ++g2) s += kvred[h2][g2][j];
        kvpart[(size_t)blockIdx.x * 192 + tid] = s;
    }
#undef STAGE
#undef STEP_BODY
}

// ---------------- reduce kv partials (deterministic) ----------------
__global__ void k_red(const float* __restrict__ kvpart, float* __restrict__ kvstate) {
    int idx = blockIdx.x * 256 + threadIdx.x;   // 768 = B*H*6
    if (idx >= BB * HH * 6) return;
    int b = idx / 192, r = idx % 192;
    float s = 0.f;
    for (int blk = 0; blk < 128; ++blk)
        s += kvpart[(size_t)(b * 128 + blk) * 192 + r];
    kvstate[idx] = s;  // [b][h][6]
}

// ---------------- out-projection GEMM (attn inline) + residual -------------
#define CEP_STRIDE 260
__global__ __launch_bounds__(512, 4) void k_out(
    const float* __restrict__ qfeat, const float* __restrict__ kvstate,
    const ushort_t* __restrict__ W2, const float* __restrict__ out_b,
    const float* __restrict__ x, float* __restrict__ out) {
    __shared__ float skv[192];
    __shared__ __align__(16) float cep[32 * CEP_STRIDE];   // 33280 B
    const int tid = threadIdx.x, wave = tid >> 6, lane = tid & 63;
    const int rg = wave & 1, cq = wave >> 1;
    const int mb = blockIdx.x >> 1, nb = blockIdx.x & 1;
    const int m0 = mb * 32;
    const int n0 = nb * 1024;
    const int b = m0 >> 12;
    if (tid < 192) skv[tid] = kvstate[b * 192 + tid];

    const int arow = m0 + rg * 16 + (lane & 15);
    const int ksub = 8 * (lane >> 4);
    float4 qa0 = *(const float4*)(qfeat + (size_t)arow * KKC + ksub);
    float4 qa1 = *(const float4*)(qfeat + (size_t)arow * KKC + ksub + 4);
    float4 qb0 = *(const float4*)(qfeat + (size_t)arow * KKC + 32 + ksub);
    float4 qb1 = *(const float4*)(qfeat + (size_t)arow * KKC + 32 + ksub + 4);
    __syncthreads();

    union { ushort_t u[8]; s16x8 v; } ca, cb;
    {
        float qs[8] = {qa0.x,qa0.y,qa0.z,qa0.w,qa1.x,qa1.y,qa1.z,qa1.w};
        float rs[8] = {qb0.x,qb0.y,qb0.z,qb0.w,qb1.x,qb1.y,qb1.z,qb1.w};
        #pragma unroll
        for (int e = 0; e < 8; e += 2) {
            int h = (ksub + e) >> 1;
            const float* kv = skv + h * 6;
            float q0 = qs[e], q1 = qs[e+1];
            float inv = 1.f / (q0 * kv[4] + q1 * kv[5] + 1e-8f);
            ca.u[e]   = f2bf((q0 * kv[0] + q1 * kv[2]) * inv);
            ca.u[e+1] = f2bf((q0 * kv[1] + q1 * kv[3]) * inv);
            const float* kw = skv + (h + 16) * 6;
            float p0 = rs[e], p1 = rs[e+1];
            float iw = 1.f / (p0 * kw[4] + p1 * kw[5] + 1e-8f);
            cb.u[e]   = f2bf((p0 * kw[0] + p1 * kw[2]) * iw);
            cb.u[e+1] = f2bf((p0 * kw[1] + p1 * kw[3]) * iw);
        }
    }

    f32x4 acc[16];
    #pragma unroll
    for (int j = 0; j < 16; ++j) acc[j] = (f32x4){0.f, 0.f, 0.f, 0.f};
    #pragma unroll
    for (int j = 0; j < 16; ++j) {
        int Fg = (n0 >> 4) + cq + 4 * j;
        s16x8 b0 = *(const s16x8*)(W2 + ((size_t)(Fg * 2 + 0) * 64 + lane) * 8);
        s16x8 b1 = *(const s16x8*)(W2 + ((size_t)(Fg * 2 + 1) * 64 + lane) * 8);
        mfma16(acc[j], ca.v, b0);
        mfma16(acc[j], cb.v, b1);
    }

    const int wrow = rg * 16 + 4 * (lane >> 4);
    #pragma unroll
    for (int n = 0; n < 4; ++n) {
        #pragma unroll
        for (int i = 0; i < 4; ++i) {
            int col = cq * 16 + i * 64 + (lane & 15);
            #pragma unroll
            for (int r = 0; r < 4; ++r)
                cep[(wrow + r) * CEP_STRIDE + col] = acc[4 * n + i][r];
        }
        __syncthreads();
        #pragma unroll
        for (int p = 0; p < 4; ++p) {
            int row = p * 8 + (tid >> 6);
            int c4 = tid & 63;
            float4 c = *(const float4*)(cep + row * CEP_STRIDE + c4 * 4);
            int gcol = n0 + n * 256 + c4 * 4;
            size_t off = (size_t)(m0 + row) * DD + gcol;
            float4 xr = *(const float4*)(x + off);
            float4 ob = *(const float4*)(out_b + gcol);
            float4 o;
            o.x = c.x + ob.x + xr.x; o.y = c.y + ob.y + xr.y;
            o.z = c.z + ob.z + xr.z; o.w = c.w + ob.w + xr.w;
            *(float4*)(out + off) = o;
        }
        __syncthreads();
    }
}

extern "C" void kernel_launch(void* const* d_in, const int* in_sizes, int n_in,
                              void* d_out, int out_size, void* d_ws, size_t ws_size,
                              hipStream_t stream) {
    const float* x     = (const float*)d_in[0];
    const float* nw    = (const float*)d_in[1];
    const float* nb    = (const float*)d_in[2];
    const float* qkv_w = (const float*)d_in[3];
    const float* qkv_b = (const float*)d_in[4];
    const float* fm_w  = (const float*)d_in[5];
    const float* fm_b  = (const float*)d_in[6];
    const float* out_w = (const float*)d_in[7];
    const float* out_b = (const float*)d_in[8];
    float* out = (float*)d_out;

    char* ws = (char*)d_ws;
    ushort_t* W1 = (ushort_t*)ws;     ws += (size_t)NQKV * DD * 2;        // 786432 B
    ushort_t* W2 = (ushort_t*)ws;     ws += (size_t)DD * KKC * 2;         // 262144 B
    float* qfeat = (float*)ws;        ws += (size_t)NT * KKC * 4;         // 4 MiB
    float* kvpart = (float*)ws;       ws += (size_t)512 * 192 * 4;        // 393216 B
    float* kvstate = (float*)ws;      ws += (size_t)BB * HH * 6 * 4;      // 3072 B
    float* Svec = (float*)ws;         ws += (size_t)NQKV * 4;             // 768 B
    float* qb2 = (float*)ws;          ws += (size_t)NQKV * 4;             // 768 B

    hipFuncSetAttribute((const void*)k_qkv,
                        hipFuncAttributeMaxDynamicSharedMemorySize, 2 * BUF2);

    k_pre<<<256, 256, 0, stream>>>(qkv_w, nw, out_w, W1, W2);
    k_colsum<<<48, 256, 0, stream>>>(qkv_w, nw, nb, qkv_b, Svec, qb2);
    k_qkv<<<NT / QB, 512, 2 * BUF2, stream>>>(x, W1, Svec, qb2, fm_w, fm_b, qfeat, kvpart);
    k_red<<<3, 256, 0, stream>>>(kvpart, kvstate);
    k_out<<<(NT / 32) * 2, 512, 0, stream>>>(qfeat, kvstate, W2, out_b, x, out);
}

// Round 13
// 121.240 us; speedup vs baseline: 1.0365x; 1.0365x over previous
//
#include <hip/hip_runtime.h>
#include <hip/hip_bf16.h>
#include <stdint.h>

typedef unsigned short ushort_t;

#define BB 4
#define SS 4096
#define DD 2048
#define KKC 64      // K channels
#define HH 32
#define NT (BB*SS)  // 16384 tokens
#define NQKV 192
#define QB 64       // tokens per k_qkv block

typedef float f32x4 __attribute__((ext_vector_type(4)));
typedef short s16x8 __attribute__((ext_vector_type(8)));

__device__ __forceinline__ ushort_t f2bf(float f) {
    union { float f; uint32_t u; } c; c.f = f;
    uint32_t u = c.u + 0x7fffu + ((c.u >> 16) & 1u);
    return (ushort_t)(u >> 16);
}
__device__ __forceinline__ float bf2f(ushort_t b) {
    union { uint32_t u; float f; } c; c.u = (uint32_t)b << 16; return c.f;
}

__device__ __forceinline__ uint32_t cvtpk(float lo, float hi) {
    uint32_t r;
    asm("v_cvt_pk_bf16_f32 %0, %1, %2" : "=v"(r) : "v"(lo), "v"(hi));
    return r;
}

// D = A(16x32) * B(32x16) + D, bf16 inputs, f32 acc.
// A lane map: row = l&15, k = 8*(l>>4)+e. B: col = l&15, k = 8*(l>>4)+e.
// C/D: col = l&15, row = 4*(l>>4)+reg.
__device__ __forceinline__ void mfma16(f32x4& d, s16x8 a, s16x8 b) {
    asm volatile("v_mfma_f32_16x16x32_bf16 %0, %1, %2, %0" : "+v"(d) : "v"(a), "v"(b));
}

// -------- merged weight pre-convert + per-col sums --------------------------
// blocks 0..255:  W1' entry E: lane=E&63, f=(E>>6)%12, g=(E>>6)/12
//   col=f*16+(lane&15); k0=g*32+8*(lane>>4); holds qkv_w[col][k]*norm_w[k]
//   (E>=49152 -> W2: n=F*16+(lane&15); k0=kk*32+8*(lane>>4))
// blocks 256..303: S[col]=sum_k bf16(qkv_w*nw); qb2[col]=sum nb*qkv_w + qkv_b
__global__ __launch_bounds__(256) void k_pre(
    const float* __restrict__ qkv_w, const float* __restrict__ nw,
    const float* __restrict__ nb, const float* __restrict__ qkv_b,
    const float* __restrict__ out_w,
    ushort_t* __restrict__ W1, ushort_t* __restrict__ W2,
    float* __restrict__ S, float* __restrict__ qb2) {
    int bid = blockIdx.x;
    if (bid < 256) {
        int E = bid * 256 + threadIdx.x;
        if (E < 49152) {
            int lane = E & 63; int rest = E >> 6;
            int f = rest % 12, g = rest / 12;
            int col = f * 16 + (lane & 15);
            int k0 = g * 32 + 8 * (lane >> 4);
            const float* src = qkv_w + (size_t)col * DD + k0;
            const float* wp = nw + k0;
            union { ushort_t u[8]; uint4 v; } cv;
            #pragma unroll
            for (int e = 0; e < 8; ++e) cv.u[e] = f2bf(src[e] * wp[e]);
            *(uint4*)(W1 + (size_t)E * 8) = cv.v;
        } else {
            int E2 = E - 49152;   // 16384 entries
            int lane = E2 & 63; int rest = E2 >> 6;
            int kk = rest & 1, F = rest >> 1;
            int n = F * 16 + (lane & 15);
            int k0 = kk * 32 + 8 * (lane >> 4);
            const float* src = out_w + (size_t)n * KKC + k0;
            union { ushort_t u[8]; uint4 v; } cv;
            #pragma unroll
            for (int e = 0; e < 8; ++e) cv.u[e] = f2bf(src[e]);
            *(uint4*)(W2 + (size_t)E2 * 8) = cv.v;
        }
    } else {
        int col = (bid - 256) * 4 + (threadIdx.x >> 6);   // 48 blocks -> 192 cols
        int lane = threadIdx.x & 63;
        float s = 0.f, qb = 0.f;
        for (int j = 0; j < 32; ++j) {
            int k = j * 64 + lane;
            float w = qkv_w[(size_t)col * DD + k];
            s += bf2f(f2bf(w * nw[k]));
            qb += nb[k] * w;
        }
        #pragma unroll
        for (int off = 32; off >= 1; off >>= 1) {
            s += __shfl_xor(s, off);
            qb += __shfl_xor(qb, off);
        }
        if (lane == 0) { S[col] = s; qb2[col] = qb + qkv_b[col]; }
    }
}

// ------- fused (LN-folded) QKV GEMM, BARRIER-FREE main loop -----------------
// grid 256 x 512 thr = 8 waves: rg = wave&3 (rows rg*16..+15), ch = wave>>2
// (96 cols = 6 frags). BK=64, 32 steps, unroll-2 reg ping-pong.
// B: W1 global->reg direct (L2-resident; 12 coalesced 1KB loads/step/wave).
// A: wave-PRIVATE LDS bounce: coalesced 4-row f32 loads -> cvtpk bf16 ->
//    swizzled ds_write_b64 -> ds_read_b128 fragments. No cross-wave barriers;
//    compiler inserts counted waitcnts. launch_bounds(512,2) authorizes the
//    ~170 VGPR needed to keep both B buffers + x stage in registers.
__global__ __launch_bounds__(512, 2) void k_qkv(
    const float* __restrict__ x, const ushort_t* __restrict__ W1,
    const float* __restrict__ S, const float* __restrict__ qb2,
    const float* __restrict__ fm_w, const float* __restrict__ fm_b,
    float* __restrict__ qfeat,          // [NT][64]
    float* __restrict__ kvpart)         // [256 blocks][192]
{
    __shared__ __align__(16) union {
        ushort_t xb[8][2][16][64];      // 8 waves x 2 parity x 16 rows x 64 bf16 = 32KB
        float cep[QB][NQKV];            // 48KB (overlay after loop, post-barrier)
    } sm;
    __shared__ float kvred[32][16][6];   // 12288 B
    __shared__ float stats[QB][2];       // 512 B

    const int tid = threadIdx.x;
    const int wave = tid >> 6, lane = tid & 63;
    const int rg = wave & 3, ch = wave >> 2;
    const int m0 = blockIdx.x * QB;
    const int fbase = ch * 6;
    const int l15 = lane & 15, q4 = lane >> 4;
    const bool doStats = (ch == 0);

    // x load geometry: load i covers rows rg*16 + i*4 + q4, 16B granule l15
    const float* xbase = x + (size_t)(m0 + rg * 16 + q4) * DD + l15 * 4;
    // ds_write byte offsets (8B each), row r = i*4+q4, swizzled 16B slots
    int wb[4];
    #pragma unroll
    for (int i = 0; i < 4; ++i) {
        int r = i * 4 + q4;
        wb[i] = r * 128 + ((l15 >> 1) ^ (r & 7)) * 16 + (l15 & 1) * 8;
    }
    const s16x8* __restrict__ Wp = (const s16x8*)W1;

    f32x4 acc[6];
    #pragma unroll
    for (int j = 0; j < 6; ++j) acc[j] = (f32x4){0.f, 0.f, 0.f, 0.f};
    float st1[4] = {0.f, 0.f, 0.f, 0.f}, st2[4] = {0.f, 0.f, 0.f, 0.f};

#define LOADX(T, X) do { \
        _Pragma("unroll") \
        for (int i_ = 0; i_ < 4; ++i_) \
            X[i_] = *(const float4*)(xbase + (size_t)(i_ * 4) * DD + (T) * 64); \
    } while (0)

#define LOADB(T, D) do { \
        _Pragma("unroll") \
        for (int kb_ = 0; kb_ < 2; ++kb_) \
        { _Pragma("unroll") \
          for (int cf_ = 0; cf_ < 6; ++cf_) \
            D[kb_][cf_] = Wp[((size_t)(2 * (T) + kb_) * 12 + fbase + cf_) * 64 + lane]; } \
    } while (0)

#define CVTW(T, X) do { \
        char* xbw_ = (char*)&sm.xb[wave][(T) & 1][0][0]; \
        _Pragma("unroll") \
        for (int i_ = 0; i_ < 4; ++i_) { \
            if (doStats) { \
                st1[i_] += X[i_].x + X[i_].y + X[i_].z + X[i_].w; \
                st2[i_] += X[i_].x*X[i_].x + X[i_].y*X[i_].y \
                         + X[i_].z*X[i_].z + X[i_].w*X[i_].w; \
            } \
            uint2 w_; \
            w_.x = cvtpk(X[i_].x, X[i_].y); \
            w_.y = cvtpk(X[i_].z, X[i_].w); \
            *(uint2*)(xbw_ + wb[i_]) = w_; \
        } \
    } while (0)

#define AREAD(T, AF) do { \
        const char* xbr_ = (const char*)&sm.xb[wave][(T) & 1][0][0]; \
        _Pragma("unroll") \
        for (int kb_ = 0; kb_ < 2; ++kb_) \
            AF[kb_] = *(const s16x8*)(xbr_ + l15 * 128 + (((kb_ * 4 + q4) ^ (l15 & 7)) << 4)); \
    } while (0)

#define MM(AF, D) do { \
        _Pragma("unroll") \
        for (int kb_ = 0; kb_ < 2; ++kb_) \
        { _Pragma("unroll") \
          for (int cf_ = 0; cf_ < 6; ++cf_) \
            mfma16(acc[cf_], AF[kb_], D[kb_][cf_]); } \
    } while (0)

    float4 xA[4], xB[4];
    s16x8 Ba[2][6], Bb[2][6], af[2];

    LOADX(0, xA);
    LOADB(0, Ba);
    CVTW(0, xA);                         // stats + cvt + ds_write parity0

    for (int tp = 0; tp < 16; ++tp) {
        const int t0 = 2 * tp, t1 = t0 + 1;
        // even step t0: parity0, B in Ba
        LOADX(t1, xB); LOADB(t1, Bb);    // prefetch odd step
        AREAD(t0, af); MM(af, Ba);
        CVTW(t1, xB);                    // write x(t1) -> parity1
        // odd step t1: parity1, B in Bb
        if (t1 < 31) { LOADX(t1 + 1, xA); LOADB(t1 + 1, Ba); }
        AREAD(t1, af); MM(af, Bb);
        if (t1 < 31) CVTW(t1 + 1, xA);   // write x(t1+1) -> parity0
    }
#undef LOADX
#undef LOADB
#undef CVTW
#undef AREAD
#undef MM

    // ---- stats finalize (ch==0 waves own all 64 rows exclusively)
    if (doStats) {
        #pragma unroll
        for (int i = 0; i < 4; ++i) {
            float s1 = st1[i], s2 = st2[i];
            s1 += __shfl_xor(s1, 1); s2 += __shfl_xor(s2, 1);
            s1 += __shfl_xor(s1, 2); s2 += __shfl_xor(s2, 2);
            s1 += __shfl_xor(s1, 4); s2 += __shfl_xor(s2, 4);
            s1 += __shfl_xor(s1, 8); s2 += __shfl_xor(s2, 8);
            if (l15 == 0) {
                int row = rg * 16 + i * 4 + q4;
                float mu = s1 * (1.f / DD);
                float var = s2 * (1.f / DD) - mu * mu;
                stats[row][0] = mu;
                stats[row][1] = rsqrtf(var + 1e-5f);
            }
        }
    }
    __syncthreads();    // all xb reads done block-wide; safe to overlay cep

    // ---- C -> cep (wave owns rows rg*16..+15, cols fbase*16..+95)
    #pragma unroll
    for (int j = 0; j < 6; ++j) {
        int col = (fbase + j) * 16 + l15;
        int rbase = rg * 16 + q4 * 4;
        #pragma unroll
        for (int r = 0; r < 4; ++r)
            sm.cep[rbase + r][col] = acc[j][r];
    }
    __syncthreads();

    // ---- per (token, head): LN-affine + feature map + qfeat + kv partials
    const int h = tid & 31, gg = tid >> 5;     // gg 0..15, 4 tokens each
    const float fm00 = fm_w[0], fm01 = fm_w[1], fm10 = fm_w[2], fm11 = fm_w[3];
    const float fb0 = fm_b[0], fb1 = fm_b[1];
    const float Sq0 = S[2*h],      Sq1 = S[2*h+1],      cq0 = qb2[2*h],      cq1 = qb2[2*h+1];
    const float Sk0 = S[64+2*h],   Sk1 = S[64+2*h+1],   ck0 = qb2[64+2*h],   ck1 = qb2[64+2*h+1];
    const float Sv0 = S[128+2*h],  Sv1 = S[128+2*h+1],  cv0 = qb2[128+2*h],  cv1 = qb2[128+2*h+1];
    float kv00=0, kv01=0, kv10=0, kv11=0, ks0=0, ks1=0;
    #pragma unroll
    for (int i = 0; i < 4; ++i) {
        int tt = gg * 4 + i;
        float mu = stats[tt][0], rs = stats[tt][1];
        float f = mu * rs;
        float q0 = rs * sm.cep[tt][2*h]      - f * Sq0 + cq0;
        float q1 = rs * sm.cep[tt][2*h+1]    - f * Sq1 + cq1;
        float k0 = rs * sm.cep[tt][64+2*h]   - f * Sk0 + ck0;
        float k1 = rs * sm.cep[tt][64+2*h+1] - f * Sk1 + ck1;
        float v0 = rs * sm.cep[tt][128+2*h]  - f * Sv0 + cv0;
        float v1 = rs * sm.cep[tt][128+2*h+1]- f * Sv1 + cv1;
        float qp0 = fmaxf(fm00*q0 + fm01*q1 + fb0, 0.f);
        float qp1 = fmaxf(fm10*q0 + fm11*q1 + fb1, 0.f);
        float kp0 = fmaxf(fm00*k0 + fm01*k1 + fb0, 0.f);
        float kp1 = fmaxf(fm10*k0 + fm11*k1 + fb1, 0.f);
        *(float2*)(qfeat + (size_t)(m0 + tt) * KKC + 2*h) = make_float2(qp0, qp1);
        kv00 += kp0*v0; kv01 += kp0*v1; kv10 += kp1*v0; kv11 += kp1*v1;
        ks0 += kp0; ks1 += kp1;
    }
    kvred[h][gg][0]=kv00; kvred[h][gg][1]=kv01; kvred[h][gg][2]=kv10;
    kvred[h][gg][3]=kv11; kvred[h][gg][4]=ks0;  kvred[h][gg][5]=ks1;
    __syncthreads();
    if (tid < 192) {
        int h2 = tid / 6, j = tid % 6;
        float s = 0.f;
        #pragma unroll
        for (int g2 = 0; g2 < 16; ++g2) s += kvred[h2][g2][j];
        kvpart[(size_t)blockIdx.x * 192 + tid] = s;
    }
}

// ---------------- out-projection GEMM (kv reduce + attn inline) + residual --
#define CEP_STRIDE 260
__global__ __launch_bounds__(512, 4) void k_out(
    const float* __restrict__ qfeat, const float* __restrict__ kvpart,
    const ushort_t* __restrict__ W2, const float* __restrict__ out_b,
    const float* __restrict__ x, float* __restrict__ out) {
    __shared__ float skv[192];
    __shared__ __align__(16) float cep[32 * CEP_STRIDE];   // 33280 B
    const int tid = threadIdx.x, wave = tid >> 6, lane = tid & 63;
    const int rg = wave & 1, cq = wave >> 1;
    const int mb = blockIdx.x >> 1, nb = blockIdx.x & 1;
    const int m0 = mb * 32;
    const int n0 = nb * 1024;
    const int b = m0 >> 12;

    // inline kv reduction: batch b owns k_qkv blocks [b*64, b*64+64)
    if (tid < 192) {
        float s = 0.f;
        #pragma unroll 8
        for (int j = 0; j < 64; ++j)
            s += kvpart[(size_t)(b * 64 + j) * 192 + tid];
        skv[tid] = s;
    }

    const int arow = m0 + rg * 16 + (lane & 15);
    const int ksub = 8 * (lane >> 4);
    float4 qa0 = *(const float4*)(qfeat + (size_t)arow * KKC + ksub);
    float4 qa1 = *(const float4*)(qfeat + (size_t)arow * KKC + ksub + 4);
    float4 qb0 = *(const float4*)(qfeat + (size_t)arow * KKC + 32 + ksub);
    float4 qb1 = *(const float4*)(qfeat + (size_t)arow * KKC + 32 + ksub + 4);
    __syncthreads();

    union { ushort_t u[8]; s16x8 v; } ca, cb;
    {
        float qs[8] = {qa0.x,qa0.y,qa0.z,qa0.w,qa1.x,qa1.y,qa1.z,qa1.w};
        float rs[8] = {qb0.x,qb0.y,qb0.z,qb0.w,qb1.x,qb1.y,qb1.z,qb1.w};
        #pragma unroll
        for (int e = 0; e < 8; e += 2) {
            int h = (ksub + e) >> 1;
            const float* kv = skv + h * 6;
            float q0 = qs[e], q1 = qs[e+1];
            float inv = 1.f / (q0 * kv[4] + q1 * kv[5] + 1e-8f);
            ca.u[e]   = f2bf((q0 * kv[0] + q1 * kv[2]) * inv);
            ca.u[e+1] = f2bf((q0 * kv[1] + q1 * kv[3]) * inv);
            const float* kw = skv + (h + 16) * 6;
            float p0 = rs[e], p1 = rs[e+1];
            float iw = 1.f / (p0 * kw[4] + p1 * kw[5] + 1e-8f);
            cb.u[e]   = f2bf((p0 * kw[0] + p1 * kw[2]) * iw);
            cb.u[e+1] = f2bf((p0 * kw[1] + p1 * kw[3]) * iw);
        }
    }

    f32x4 acc[16];
    #pragma unroll
    for (int j = 0; j < 16; ++j) acc[j] = (f32x4){0.f, 0.f, 0.f, 0.f};
    #pragma unroll
    for (int j = 0; j < 16; ++j) {
        int Fg = (n0 >> 4) + cq + 4 * j;
        s16x8 b0 = *(const s16x8*)(W2 + ((size_t)(Fg * 2 + 0) * 64 + lane) * 8);
        s16x8 b1 = *(const s16x8*)(W2 + ((size_t)(Fg * 2 + 1) * 64 + lane) * 8);
        mfma16(acc[j], ca.v, b0);
        mfma16(acc[j], cb.v, b1);
    }

    const int wrow = rg * 16 + 4 * (lane >> 4);
    #pragma unroll
    for (int n = 0; n < 4; ++n) {
        #pragma unroll
        for (int i = 0; i < 4; ++i) {
            int col = cq * 16 + i * 64 + (lane & 15);
            #pragma unroll
            for (int r = 0; r < 4; ++r)
                cep[(wrow + r) * CEP_STRIDE + col] = acc[4 * n + i][r];
        }
        __syncthreads();
        #pragma unroll
        for (int p = 0; p < 4; ++p) {
            int row = p * 8 + (tid >> 6);
            int c4 = tid & 63;
            float4 c = *(const float4*)(cep + row * CEP_STRIDE + c4 * 4);
            int gcol = n0 + n * 256 + c4 * 4;
            size_t off = (size_t)(m0 + row) * DD + gcol;
            float4 xr = *(const float4*)(x + off);
            float4 ob = *(const float4*)(out_b + gcol);
            float4 o;
            o.x = c.x + ob.x + xr.x; o.y = c.y + ob.y + xr.y;
            o.z = c.z + ob.z + xr.z; o.w = c.w + ob.w + xr.w;
            *(float4*)(out + off) = o;
        }
        __syncthreads();
    }
}

extern "C" void kernel_launch(void* const* d_in, const int* in_sizes, int n_in,
                              void* d_out, int out_size, void* d_ws, size_t ws_size,
                              hipStream_t stream) {
    const float* x     = (const float*)d_in[0];
    const float* nw    = (const float*)d_in[1];
    const float* nb    = (const float*)d_in[2];
    const float* qkv_w = (const float*)d_in[3];
    const float* qkv_b = (const float*)d_in[4];
    const float* fm_w  = (const float*)d_in[5];
    const float* fm_b  = (const float*)d_in[6];
    const float* out_w = (const float*)d_in[7];
    const float* out_b = (const float*)d_in[8];
    float* out = (float*)d_out;

    char* ws = (char*)d_ws;
    ushort_t* W1 = (ushort_t*)ws;     ws += (size_t)NQKV * DD * 2;        // 786432 B
    ushort_t* W2 = (ushort_t*)ws;     ws += (size_t)DD * KKC * 2;         // 262144 B
    float* qfeat = (float*)ws;        ws += (size_t)NT * KKC * 4;         // 4 MiB
    float* kvpart = (float*)ws;       ws += (size_t)256 * 192 * 4;        // 196608 B
    float* Svec = (float*)ws;         ws += (size_t)NQKV * 4;             // 768 B
    float* qb2 = (float*)ws;          ws += (size_t)NQKV * 4;             // 768 B

    k_pre<<<304, 256, 0, stream>>>(qkv_w, nw, nb, qkv_b, out_w, W1, W2, Svec, qb2);
    k_qkv<<<NT / QB, 512, 0, stream>>>(x, W1, Svec, qb2, fm_w, fm_b, qfeat, kvpart);
    k_out<<<(NT / 32) * 2, 512, 0, stream>>>(qfeat, kvpart, W2, out_b, x, out);
}